// Round 10
// baseline (513.012 us; speedup 1.0000x reference)
//
#include <hip/hip_runtime.h>
#include <hip/hip_bf16.h>

#define SCALE 3.5f
#define TJ 512            // square tile size (points)
#define THREADS 256       // 4 waves per block
#define MAGIC 0x13572468  // != 0xAAAAAAAA poison

typedef __attribute__((ext_vector_type(8))) short short8;    // 8 bf16 = 4 VGPRs
typedef __attribute__((ext_vector_type(4))) short short4v;   // 4 bf16 = 2 VGPRs
typedef __attribute__((ext_vector_type(16))) float float16v; // 32x32 accumulator
typedef __attribute__((ext_vector_type(2))) float float2v;   // packed-f32 pair

// fp32 -> bf16 round-to-nearest-even (bit trick; inputs finite)
__device__ inline short bfh(float v) {
    union { float f; unsigned u; } x; x.f = v;
    unsigned r = (x.u + 0x7fffu + ((x.u >> 16) & 1u)) >> 16;
    return (short)r;
}
__device__ inline float bff(short s) {
    union { float f; unsigned u; } x; x.u = ((unsigned)(unsigned short)s) << 16;
    return x.f;
}

// LDS layout (short4v entries, 8B each):
//   A records: point i -> 16B [ahi,bhi,chi,1 | alo,blo,clo,0] at entries 2i,2i+1
//   BHI: [xh,yh,1,fh] per col point ; BLO: [xl,yl,0,fl]
#define AREC 0      // 1024 entries (512 rows * 16B), staged ONCE per chunk
#define BHI  1024   // 512 entries, restaged per tile
#define BLO  1536   // 512 entries

// ws: double pZ[nbC] | double pC[nbC] | double pS[nbC] | int flags[nbC]
//     (0xAA poison != MAGIC; no host-side init — proven contract)

// (256,4): register budget 128/lane — a (256,8) cap forced inner-loop scratch
// spill in round 6 (WRITE_SIZE 89KB -> 460MB). D0-D3 ILP needs ~110 regs.
__global__ __launch_bounds__(THREADS, 4)
void fused_kernel(const float* __restrict__ emb,
                  const float* __restrict__ p,
                  const int* __restrict__ heads,
                  const int* __restrict__ tails,
                  int e, int n, int nt, int nbC,
                  double* __restrict__ pZ,
                  double* __restrict__ pC,
                  double* __restrict__ pS,
                  int* __restrict__ flags,
                  float* __restrict__ out) {
    const int bid = blockIdx.x;
    const float2* e2 = (const float2*)emb;
    const int lane = threadIdx.x & 63, wid = threadIdx.x >> 6;

    if (bid < nbC) {
        // ===== worker: 2 same-row Z-tiles (32x32x16 MFMA) + an edge slice =====
        // t_ij = 1+|pi-pj|^2 = dot([ai,bi,ci,1],[xj,yj,1,fj]); scaled coords.
        // bf16 hi/lo split both sides; K=16 packs all 4 cross-products:
        //   k0-3: Ahi*Bhi  k4-7: Alo*Bhi  k8-11: Ahi*Blo  k12-15: Alo*Blo
        // Output layout irrelevant: we sum all 16 accumulator elements.
        int c = bid, ti = 0;
        for (;;) {                       // row search: row ti has (nt-ti+1)>>1 chunks
            int rc = (nt - ti + 1) >> 1;
            if (c < rc) break;
            c -= rc; ++ti;
        }
        const int tj0 = ti + 2 * c;
        const int has2 = (tj0 + 1) < nt;
        const int ibase = ti * TJ, jbase0 = tj0 * TJ, jbase1 = (tj0 + 1) * TJ;

        __shared__ __align__(16) short4v lds[2048];
        const short ONE = (short)0x3F80;  // bf16 1.0
        const short8* A8 = (const short8*)lds;
        const int tid = threadIdx.x;

        // ---- stage A (once) + B of tile 1 ----
        {
            float2 v0 = e2[ibase + tid], v1 = e2[ibase + tid + 256];
            float2 u0 = e2[jbase0 + tid], u1 = e2[jbase0 + tid + 256];
#define PUTA(k, v)                                                            \
            {                                                                 \
                float X = (v).x * SCALE, Y = (v).y * SCALE;                   \
                float A = -2.0f * X, B = -2.0f * Y;                           \
                float C = fmaf(X, X, fmaf(Y, Y, 1.0f));                       \
                short ah = bfh(A), bh = bfh(B), ch = bfh(C);                  \
                lds[AREC + 2 * (k)]     = (short4v){ah, bh, ch, ONE};         \
                lds[AREC + 2 * (k) + 1] = (short4v){bfh(A - bff(ah)),         \
                    bfh(B - bff(bh)), bfh(C - bff(ch)), 0};                   \
            }
#define PUTB(k, u)                                                            \
            {                                                                 \
                float X = (u).x * SCALE, Y = (u).y * SCALE;                   \
                float F = fmaf(X, X, Y * Y);                                  \
                short xh = bfh(X), yh = bfh(Y), fh = bfh(F);                  \
                lds[BHI + (k)] = (short4v){xh, yh, ONE, fh};                  \
                lds[BLO + (k)] = (short4v){bfh(X - bff(xh)),                  \
                    bfh(Y - bff(yh)), 0, bfh(F - bff(fh))};                   \
            }
            PUTA(tid, v0) PUTA(tid + 256, v1)
            PUTB(tid, u0) PUTB(tid + 256, u1)
        }
        // ---- issue tile-2 B prefetch NOW: latency hides under tile-1 compute ----
        float2 pb0, pb1;
        if (has2) { pb0 = e2[jbase1 + tid]; pb1 = e2[jbase1 + tid + 256]; }
        __syncthreads();

        const int r = lane & 31;          // row/col within 32-group
        const int khalf = lane >> 5;      // 0: k0-7 (hi B), 1: k8-15 (lo B)
        const int bbase = (khalf ? BLO : BHI) + r;

        short8 afr0, afr1, afr2, afr3;    // A-frags live across both tiles
        afr0 = A8[wid * 128 + 0 * 32 + r];
        afr1 = A8[wid * 128 + 1 * 32 + r];
        afr2 = A8[wid * 128 + 2 * 32 + r];
        afr3 = A8[wid * 128 + 3 * 32 + r];

        const float16v cz = {};
        float acc = 0.0f;
        // ILP schedule per cg: prefetch next B-rec (ds latency under COMBs),
        // issue ALL 4 MFMAs into named D0..D3 (only first latency exposed),
        // then one big independent VALU block of 16 packed COMBs.
#define COMB(D, g, a)                                                         \
        {                                                                     \
            float2v lo = {D[4 * g], D[4 * g + 1]};                            \
            float2v hi = {D[4 * g + 2], D[4 * g + 3]};                        \
            float2v P = lo * hi;   /* {t0t2, t1t3} */                         \
            float2v S = lo + hi;   /* {t0+t2, t1+t3} */                       \
            float2v NUM = __builtin_shufflevector(S, S, 1, 0) * P;            \
            float num = NUM[0] + NUM[1];                                      \
            float den = P[0] * P[1];                                          \
            a = fmaf(num, __builtin_amdgcn_rcpf(den), a);                     \
        }
        auto computeTile = [&](float w) {
            float a0 = 0.0f, a1 = 0.0f, a2 = 0.0f, a3 = 0.0f;
            short4v rec = lds[bbase];               // cg=0 B-record
#pragma unroll 4
            for (int cg = 0; cg < TJ / 32; ++cg) {
                short8 bfr = __builtin_shufflevector(rec, rec,
                                                     0, 1, 2, 3, 0, 1, 2, 3);
                if (cg + 1 < TJ / 32) rec = lds[bbase + (cg + 1) * 32];
                float16v D0 = __builtin_amdgcn_mfma_f32_32x32x16_bf16(
                                  afr0, bfr, cz, 0, 0, 0);
                float16v D1 = __builtin_amdgcn_mfma_f32_32x32x16_bf16(
                                  afr1, bfr, cz, 0, 0, 0);
                float16v D2 = __builtin_amdgcn_mfma_f32_32x32x16_bf16(
                                  afr2, bfr, cz, 0, 0, 0);
                float16v D3 = __builtin_amdgcn_mfma_f32_32x32x16_bf16(
                                  afr3, bfr, cz, 0, 0, 0);
                COMB(D0, 0, a0) COMB(D0, 1, a1) COMB(D0, 2, a2) COMB(D0, 3, a3)
                COMB(D1, 0, a0) COMB(D1, 1, a1) COMB(D1, 2, a2) COMB(D1, 3, a3)
                COMB(D2, 0, a0) COMB(D2, 1, a1) COMB(D2, 2, a2) COMB(D2, 3, a3)
                COMB(D3, 0, a0) COMB(D3, 1, a1) COMB(D3, 2, a2) COMB(D3, 3, a3)
            }
            acc = fmaf(w, (a0 + a1) + (a2 + a3), acc);
        };

        computeTile(tj0 == ti ? 1.0f : 2.0f);

        if (has2) {
            __syncthreads();   // all reads of B1 done before overwrite
            PUTB(tid, pb0) PUTB(tid + 256, pb1)
            __syncthreads();   // B2 visible
            computeTile(2.0f); // tj0+1 > ti always: off-diagonal weight
        }
#undef COMB
#undef PUTA
#undef PUTB

        // ================= edge slice (attractive + entropy) =================
        // e2 gathers are L1/L2-hot after the Z phase. Uniform slice per block.
        float accC = 0.0f, accS = 0.0f;
        {
            const int4* h4 = (const int4*)heads;
            const int4* t4 = (const int4*)tails;
            const float4* p4 = (const float4*)p;
            const int e4 = e >> 2;
            const int stride = nbC * THREADS;
            for (int idx = bid * THREADS + tid; idx < e4; idx += stride) {
                int4 h = h4[idx];
                int4 t = t4[idx];
                float4 pv = p4[idx];
                {
                    float2 a = e2[h.x], bb = e2[t.x];
                    float dx = a.x - bb.x, dy = a.y - bb.y;
                    float sq = fmaf(dx, dx, dy * dy) * (SCALE * SCALE);
                    accC += pv.x * __logf(pv.x * (1.0f + sq));
                    accS += pv.x;
                }
                {
                    float2 a = e2[h.y], bb = e2[t.y];
                    float dx = a.x - bb.x, dy = a.y - bb.y;
                    float sq = fmaf(dx, dx, dy * dy) * (SCALE * SCALE);
                    accC += pv.y * __logf(pv.y * (1.0f + sq));
                    accS += pv.y;
                }
                {
                    float2 a = e2[h.z], bb = e2[t.z];
                    float dx = a.x - bb.x, dy = a.y - bb.y;
                    float sq = fmaf(dx, dx, dy * dy) * (SCALE * SCALE);
                    accC += pv.z * __logf(pv.z * (1.0f + sq));
                    accS += pv.z;
                }
                {
                    float2 a = e2[h.w], bb = e2[t.w];
                    float dx = a.x - bb.x, dy = a.y - bb.y;
                    float sq = fmaf(dx, dx, dy * dy) * (SCALE * SCALE);
                    accC += pv.w * __logf(pv.w * (1.0f + sq));
                    accS += pv.w;
                }
            }
            for (int idx = (e4 << 2) + bid * THREADS + tid; idx < e; idx += stride) {
                int h = heads[idx], t = tails[idx];
                float pv = p[idx];
                float2 a = e2[h], bb = e2[t];
                float dx = a.x - bb.x, dy = a.y - bb.y;
                float sq = fmaf(dx, dx, dy * dy) * (SCALE * SCALE);
                accC += pv * __logf(pv * (1.0f + sq));
                accS += pv;
            }
        }

        // ================= merged 3-way reduce + single flag =================
#pragma unroll
        for (int off = 32; off > 0; off >>= 1) {
            acc  += __shfl_down(acc,  off, 64);
            accC += __shfl_down(accC, off, 64);
            accS += __shfl_down(accS, off, 64);
        }
        __shared__ float red[3][THREADS / 64];
        if (lane == 0) { red[0][wid] = acc; red[1][wid] = accC; red[2][wid] = accS; }
        __syncthreads();
        if (tid == 0) {
            float tz = 0.0f, tc = 0.0f, ts = 0.0f;
#pragma unroll
            for (int ww = 0; ww < THREADS / 64; ++ww) {
                tz += red[0][ww]; tc += red[1][ww]; ts += red[2][ww];
            }
            __hip_atomic_store(&pZ[bid], (double)tz, __ATOMIC_RELAXED,
                               __HIP_MEMORY_SCOPE_AGENT);
            __hip_atomic_store(&pC[bid], (double)tc, __ATOMIC_RELAXED,
                               __HIP_MEMORY_SCOPE_AGENT);
            __hip_atomic_store(&pS[bid], (double)ts, __ATOMIC_RELAXED,
                               __HIP_MEMORY_SCOPE_AGENT);
            __hip_atomic_store(&flags[bid], MAGIC, __ATOMIC_RELEASE,
                               __HIP_MEMORY_SCOPE_AGENT);
        }
    } else {
        // ================= finalize (spin-wait producers, reduce, emit) =========
        double lC = 0.0, lS = 0.0, lZ = 0.0;
        for (int b2 = threadIdx.x; b2 < nbC; b2 += THREADS) {
            while (__hip_atomic_load(&flags[b2], __ATOMIC_ACQUIRE,
                                     __HIP_MEMORY_SCOPE_AGENT) != MAGIC)
                __builtin_amdgcn_s_sleep(8);
            lZ += __hip_atomic_load(&pZ[b2], __ATOMIC_RELAXED,
                                    __HIP_MEMORY_SCOPE_AGENT);
            lC += __hip_atomic_load(&pC[b2], __ATOMIC_RELAXED,
                                    __HIP_MEMORY_SCOPE_AGENT);
            lS += __hip_atomic_load(&pS[b2], __ATOMIC_RELAXED,
                                    __HIP_MEMORY_SCOPE_AGENT);
        }
#pragma unroll
        for (int off = 32; off > 0; off >>= 1) {
            lC += __shfl_down(lC, off, 64);
            lS += __shfl_down(lS, off, 64);
            lZ += __shfl_down(lZ, off, 64);
        }
        __shared__ double dred[3 * (THREADS / 64)];
        if (lane == 0) { dred[wid * 3] = lC; dred[wid * 3 + 1] = lS; dred[wid * 3 + 2] = lZ; }
        __syncthreads();
        if (threadIdx.x == 0) {
            double cs = 0.0, sp = 0.0, zt = 0.0;
#pragma unroll
            for (int ww = 0; ww < THREADS / 64; ++ww) {
                cs += dred[ww * 3]; sp += dred[ww * 3 + 1]; zt += dred[ww * 3 + 2];
            }
            zt -= (double)n;  // remove self-pairs (each contributes ~1.0 exactly)
            out[0] = (float)(cs + sp * log(zt));
        }
    }
}

extern "C" void kernel_launch(void* const* d_in, const int* in_sizes, int n_in,
                              void* d_out, int out_size, void* d_ws, size_t ws_size,
                              hipStream_t stream) {
    const float* emb  = (const float*)d_in[0];
    const float* p    = (const float*)d_in[1];
    const int* heads  = (const int*)d_in[2];
    const int* tails  = (const int*)d_in[3];
    const int n = in_sizes[0] / 2;   // 32768 points (D=2)
    const int e = in_sizes[1];       // edge count

    const int nt = n / TJ;           // 64 tiles per side
    int nbC = 0;                     // same-row 2-tile chunks: sum ceil((nt-ti)/2)
    for (int r = 0; r < nt; ++r) nbC += (nt - r + 1) >> 1;   // = 1056

    double* pZ = (double*)d_ws;
    double* pC = pZ + nbC;
    double* pS = pC + nbC;
    int* flags = (int*)(pS + nbC);

    const int total = nbC + 1;       // 1057 uniform blocks, all resident
    fused_kernel<<<total, THREADS, 0, stream>>>(emb, p, heads, tails, e, n, nt,
                                                nbC, pZ, pC, pS, flags,
                                                (float*)d_out);
}

// Round 11
// 135.486 us; speedup vs baseline: 3.7865x; 3.7865x over previous
//
#include <hip/hip_runtime.h>
#include <hip/hip_bf16.h>

#define SCALE 3.5f
#define TJ 512            // square tile size (points)
#define THREADS 256       // 4 waves per block
#define MAGIC 0x13572468  // != 0xAAAAAAAA poison

typedef __attribute__((ext_vector_type(8))) short short8;    // 8 bf16 = 4 VGPRs
typedef __attribute__((ext_vector_type(4))) short short4v;   // 4 bf16 = 2 VGPRs
typedef __attribute__((ext_vector_type(16))) float float16v; // 32x32 accumulator
typedef __attribute__((ext_vector_type(2))) float float2v;   // packed-f32 pair

// fp32 -> bf16 round-to-nearest-even (bit trick; inputs finite)
__device__ inline short bfh(float v) {
    union { float f; unsigned u; } x; x.f = v;
    unsigned r = (x.u + 0x7fffu + ((x.u >> 16) & 1u)) >> 16;
    return (short)r;
}
__device__ inline float bff(short s) {
    union { float f; unsigned u; } x; x.u = ((unsigned)(unsigned short)s) << 16;
    return x.f;
}

// LDS layout (short4v entries, 8B each):
//   A records: point i -> 16B [ahi,bhi,chi,1 | alo,blo,clo,0] at entries 2i,2i+1
//   BHI: [xh,yh,1,fh] per col point ; BLO: [xl,yl,0,fl]
#define AREC 0      // 1024 entries (512 rows * 16B), staged ONCE per chunk
#define BHI  1024   // 512 entries, restaged per tile
#define BLO  1536   // 512 entries

// ws: double pZ[nbC] | double pC[nbC] | double pS[nbC] | int flags[nbC]
//     (0xAA poison != MAGIC; no host-side init — proven contract)

// (256,4): register budget 128/lane. Round-10 lesson: 4 live f32x16 D-tiles
// (64 regs) spill catastrophically; TWO (32 regs) fit — VGPR target ~70.
__global__ __launch_bounds__(THREADS, 4)
void fused_kernel(const float* __restrict__ emb,
                  const float* __restrict__ p,
                  const int* __restrict__ heads,
                  const int* __restrict__ tails,
                  int e, int n, int nt, int nbC,
                  double* __restrict__ pZ,
                  double* __restrict__ pC,
                  double* __restrict__ pS,
                  int* __restrict__ flags,
                  float* __restrict__ out) {
    const int bid = blockIdx.x;
    const float2* e2 = (const float2*)emb;
    const int lane = threadIdx.x & 63, wid = threadIdx.x >> 6;

    if (bid < nbC) {
        // ===== worker: 2 same-row Z-tiles (32x32x16 MFMA) + an edge slice =====
        // t_ij = 1+|pi-pj|^2 = dot([ai,bi,ci,1],[xj,yj,1,fj]); scaled coords.
        // bf16 hi/lo split both sides; K=16 packs all 4 cross-products:
        //   k0-3: Ahi*Bhi  k4-7: Alo*Bhi  k8-11: Ahi*Blo  k12-15: Alo*Blo
        // Output layout irrelevant: we sum all 16 accumulator elements.
        int c = bid, ti = 0;
        for (;;) {                       // row search: row ti has (nt-ti+1)>>1 chunks
            int rc = (nt - ti + 1) >> 1;
            if (c < rc) break;
            c -= rc; ++ti;
        }
        const int tj0 = ti + 2 * c;
        const int has2 = (tj0 + 1) < nt;
        const int ibase = ti * TJ, jbase0 = tj0 * TJ, jbase1 = (tj0 + 1) * TJ;

        __shared__ __align__(16) short4v lds[2048];
        const short ONE = (short)0x3F80;  // bf16 1.0
        const short8* A8 = (const short8*)lds;
        const int tid = threadIdx.x;

        // ---- stage A (once) + B of tile 1 ----
        {
            float2 v0 = e2[ibase + tid], v1 = e2[ibase + tid + 256];
            float2 u0 = e2[jbase0 + tid], u1 = e2[jbase0 + tid + 256];
#define PUTA(k, v)                                                            \
            {                                                                 \
                float X = (v).x * SCALE, Y = (v).y * SCALE;                   \
                float A = -2.0f * X, B = -2.0f * Y;                           \
                float C = fmaf(X, X, fmaf(Y, Y, 1.0f));                       \
                short ah = bfh(A), bh = bfh(B), ch = bfh(C);                  \
                lds[AREC + 2 * (k)]     = (short4v){ah, bh, ch, ONE};         \
                lds[AREC + 2 * (k) + 1] = (short4v){bfh(A - bff(ah)),         \
                    bfh(B - bff(bh)), bfh(C - bff(ch)), 0};                   \
            }
#define PUTB(k, u)                                                            \
            {                                                                 \
                float X = (u).x * SCALE, Y = (u).y * SCALE;                   \
                float F = fmaf(X, X, Y * Y);                                  \
                short xh = bfh(X), yh = bfh(Y), fh = bfh(F);                  \
                lds[BHI + (k)] = (short4v){xh, yh, ONE, fh};                  \
                lds[BLO + (k)] = (short4v){bfh(X - bff(xh)),                  \
                    bfh(Y - bff(yh)), 0, bfh(F - bff(fh))};                   \
            }
            PUTA(tid, v0) PUTA(tid + 256, v1)
            PUTB(tid, u0) PUTB(tid + 256, u1)
        }
        // ---- issue tile-2 B prefetch NOW: latency hides under tile-1 compute ----
        float2 pb0, pb1;
        if (has2) { pb0 = e2[jbase1 + tid]; pb1 = e2[jbase1 + tid + 256]; }
        __syncthreads();

        const int r = lane & 31;          // row/col within 32-group
        const int khalf = lane >> 5;      // 0: k0-7 (hi B), 1: k8-15 (lo B)
        const int bbase = (khalf ? BLO : BHI) + r;

        short8 afr0, afr1, afr2, afr3;    // A-frags live across both tiles
        afr0 = A8[wid * 128 + 0 * 32 + r];
        afr1 = A8[wid * 128 + 1 * 32 + r];
        afr2 = A8[wid * 128 + 2 * 32 + r];
        afr3 = A8[wid * 128 + 3 * 32 + r];

        const float16v cz = {};
        float acc = 0.0f;
        // 2-deep static pipeline: one MFMA always in flight while COMBing the
        // previous destination. Exactly TWO named D-tiles (32 VGPRs) — round 10
        // showed four spill. Next-cg B-record prefetched under the COMB blocks.
#define COMB(D, g, a)                                                         \
        {                                                                     \
            float2v lo = {D[4 * g], D[4 * g + 1]};                            \
            float2v hi = {D[4 * g + 2], D[4 * g + 3]};                        \
            float2v P = lo * hi;   /* {t0t2, t1t3} */                         \
            float2v S = lo + hi;   /* {t0+t2, t1+t3} */                       \
            float2v NUM = __builtin_shufflevector(S, S, 1, 0) * P;            \
            float num = NUM[0] + NUM[1];                                      \
            float den = P[0] * P[1];                                          \
            a = fmaf(num, __builtin_amdgcn_rcpf(den), a);                     \
        }
#define COMB4(D) COMB(D, 0, a0) COMB(D, 1, a1) COMB(D, 2, a2) COMB(D, 3, a3)
        auto computeTile = [&](float w) {
            float a0 = 0.0f, a1 = 0.0f, a2 = 0.0f, a3 = 0.0f;
            short4v rec = lds[bbase];               // cg=0 B-record
#pragma unroll 2
            for (int cg = 0; cg < TJ / 32; ++cg) {
                short8 bfr = __builtin_shufflevector(rec, rec,
                                                     0, 1, 2, 3, 0, 1, 2, 3);
                if (cg + 1 < TJ / 32) rec = lds[bbase + (cg + 1) * 32];
                float16v Da = __builtin_amdgcn_mfma_f32_32x32x16_bf16(
                                  afr0, bfr, cz, 0, 0, 0);
                float16v Db = __builtin_amdgcn_mfma_f32_32x32x16_bf16(
                                  afr1, bfr, cz, 0, 0, 0);
                COMB4(Da)                            // Db in flight
                Da = __builtin_amdgcn_mfma_f32_32x32x16_bf16(
                         afr2, bfr, cz, 0, 0, 0);
                COMB4(Db)                            // Da in flight
                Db = __builtin_amdgcn_mfma_f32_32x32x16_bf16(
                         afr3, bfr, cz, 0, 0, 0);
                COMB4(Da)                            // Db in flight
                COMB4(Db)                            // only exposed wait per cg
            }
            acc = fmaf(w, (a0 + a1) + (a2 + a3), acc);
        };

        computeTile(tj0 == ti ? 1.0f : 2.0f);

        if (has2) {
            __syncthreads();   // all reads of B1 done before overwrite
            PUTB(tid, pb0) PUTB(tid + 256, pb1)
            __syncthreads();   // B2 visible
            computeTile(2.0f); // tj0+1 > ti always: off-diagonal weight
        }
#undef COMB4
#undef COMB
#undef PUTA
#undef PUTB

        // ================= edge slice (attractive + entropy) =================
        // e2 gathers are L1/L2-hot after the Z phase. Uniform slice per block.
        float accC = 0.0f, accS = 0.0f;
        {
            const int4* h4 = (const int4*)heads;
            const int4* t4 = (const int4*)tails;
            const float4* p4 = (const float4*)p;
            const int e4 = e >> 2;
            const int stride = nbC * THREADS;
            for (int idx = bid * THREADS + tid; idx < e4; idx += stride) {
                int4 h = h4[idx];
                int4 t = t4[idx];
                float4 pv = p4[idx];
                {
                    float2 a = e2[h.x], bb = e2[t.x];
                    float dx = a.x - bb.x, dy = a.y - bb.y;
                    float sq = fmaf(dx, dx, dy * dy) * (SCALE * SCALE);
                    accC += pv.x * __logf(pv.x * (1.0f + sq));
                    accS += pv.x;
                }
                {
                    float2 a = e2[h.y], bb = e2[t.y];
                    float dx = a.x - bb.x, dy = a.y - bb.y;
                    float sq = fmaf(dx, dx, dy * dy) * (SCALE * SCALE);
                    accC += pv.y * __logf(pv.y * (1.0f + sq));
                    accS += pv.y;
                }
                {
                    float2 a = e2[h.z], bb = e2[t.z];
                    float dx = a.x - bb.x, dy = a.y - bb.y;
                    float sq = fmaf(dx, dx, dy * dy) * (SCALE * SCALE);
                    accC += pv.z * __logf(pv.z * (1.0f + sq));
                    accS += pv.z;
                }
                {
                    float2 a = e2[h.w], bb = e2[t.w];
                    float dx = a.x - bb.x, dy = a.y - bb.y;
                    float sq = fmaf(dx, dx, dy * dy) * (SCALE * SCALE);
                    accC += pv.w * __logf(pv.w * (1.0f + sq));
                    accS += pv.w;
                }
            }
            for (int idx = (e4 << 2) + bid * THREADS + tid; idx < e; idx += stride) {
                int h = heads[idx], t = tails[idx];
                float pv = p[idx];
                float2 a = e2[h], bb = e2[t];
                float dx = a.x - bb.x, dy = a.y - bb.y;
                float sq = fmaf(dx, dx, dy * dy) * (SCALE * SCALE);
                accC += pv * __logf(pv * (1.0f + sq));
                accS += pv;
            }
        }

        // ================= merged 3-way reduce + single flag =================
#pragma unroll
        for (int off = 32; off > 0; off >>= 1) {
            acc  += __shfl_down(acc,  off, 64);
            accC += __shfl_down(accC, off, 64);
            accS += __shfl_down(accS, off, 64);
        }
        __shared__ float red[3][THREADS / 64];
        if (lane == 0) { red[0][wid] = acc; red[1][wid] = accC; red[2][wid] = accS; }
        __syncthreads();
        if (tid == 0) {
            float tz = 0.0f, tc = 0.0f, ts = 0.0f;
#pragma unroll
            for (int ww = 0; ww < THREADS / 64; ++ww) {
                tz += red[0][ww]; tc += red[1][ww]; ts += red[2][ww];
            }
            __hip_atomic_store(&pZ[bid], (double)tz, __ATOMIC_RELAXED,
                               __HIP_MEMORY_SCOPE_AGENT);
            __hip_atomic_store(&pC[bid], (double)tc, __ATOMIC_RELAXED,
                               __HIP_MEMORY_SCOPE_AGENT);
            __hip_atomic_store(&pS[bid], (double)ts, __ATOMIC_RELAXED,
                               __HIP_MEMORY_SCOPE_AGENT);
            __hip_atomic_store(&flags[bid], MAGIC, __ATOMIC_RELEASE,
                               __HIP_MEMORY_SCOPE_AGENT);
        }
    } else {
        // ================= finalize (spin-wait producers, reduce, emit) =========
        double lC = 0.0, lS = 0.0, lZ = 0.0;
        for (int b2 = threadIdx.x; b2 < nbC; b2 += THREADS) {
            while (__hip_atomic_load(&flags[b2], __ATOMIC_ACQUIRE,
                                     __HIP_MEMORY_SCOPE_AGENT) != MAGIC)
                __builtin_amdgcn_s_sleep(8);
            lZ += __hip_atomic_load(&pZ[b2], __ATOMIC_RELAXED,
                                    __HIP_MEMORY_SCOPE_AGENT);
            lC += __hip_atomic_load(&pC[b2], __ATOMIC_RELAXED,
                                    __HIP_MEMORY_SCOPE_AGENT);
            lS += __hip_atomic_load(&pS[b2], __ATOMIC_RELAXED,
                                    __HIP_MEMORY_SCOPE_AGENT);
        }
#pragma unroll
        for (int off = 32; off > 0; off >>= 1) {
            lC += __shfl_down(lC, off, 64);
            lS += __shfl_down(lS, off, 64);
            lZ += __shfl_down(lZ, off, 64);
        }
        __shared__ double dred[3 * (THREADS / 64)];
        if (lane == 0) { dred[wid * 3] = lC; dred[wid * 3 + 1] = lS; dred[wid * 3 + 2] = lZ; }
        __syncthreads();
        if (threadIdx.x == 0) {
            double cs = 0.0, sp = 0.0, zt = 0.0;
#pragma unroll
            for (int ww = 0; ww < THREADS / 64; ++ww) {
                cs += dred[ww * 3]; sp += dred[ww * 3 + 1]; zt += dred[ww * 3 + 2];
            }
            zt -= (double)n;  // remove self-pairs (each contributes ~1.0 exactly)
            out[0] = (float)(cs + sp * log(zt));
        }
    }
}

extern "C" void kernel_launch(void* const* d_in, const int* in_sizes, int n_in,
                              void* d_out, int out_size, void* d_ws, size_t ws_size,
                              hipStream_t stream) {
    const float* emb  = (const float*)d_in[0];
    const float* p    = (const float*)d_in[1];
    const int* heads  = (const int*)d_in[2];
    const int* tails  = (const int*)d_in[3];
    const int n = in_sizes[0] / 2;   // 32768 points (D=2)
    const int e = in_sizes[1];       // edge count

    const int nt = n / TJ;           // 64 tiles per side
    int nbC = 0;                     // same-row 2-tile chunks: sum ceil((nt-ti)/2)
    for (int r = 0; r < nt; ++r) nbC += (nt - r + 1) >> 1;   // = 1056

    double* pZ = (double*)d_ws;
    double* pC = pZ + nbC;
    double* pS = pC + nbC;
    int* flags = (int*)(pS + nbC);

    const int total = nbC + 1;       // 1057 uniform blocks, all resident
    fused_kernel<<<total, THREADS, 0, stream>>>(emb, p, heads, tails, e, n, nt,
                                                nbC, pZ, pC, pS, flags,
                                                (float*)d_out);
}